// Round 5
// baseline (143.699 us; speedup 1.0000x reference)
//
#include <hip/hip_runtime.h>
#include <hip/hip_bf16.h>

typedef unsigned short u16;
typedef __attribute__((ext_vector_type(8))) short short8;
typedef __attribute__((ext_vector_type(4))) float f32x4;
typedef __attribute__((ext_vector_type(4))) unsigned int u32x4;

#define CC    128
#define WW    48
#define HW2   2304      // 48*48
#define NHW   46
#define NQ    2116      // 46*46
#define MROWS 2176      // padded M rows per batch (17*128)
#define NPK   2176      // rows per candidate set inside B
#define NTOT  4352      // 17*256
#define KK    1152      // 128*9
#define NKT   36        // K-tiles of 32
#define NHALF 68        // 17 N-tiles * 4 wave-columns
#define BATCH 2

__device__ __forceinline__ u16 f2bf(float f) {
  union { float f; unsigned u; } x; x.f = f;
  unsigned r = (x.u + 0x7fffu + ((x.u >> 16) & 1u)) >> 16;
  return (u16)r;
}

// ---- kernel 1: fused invnorm + im2col (bf16, pre-swizzled chunks), LDS-staged ----
// Row r holds K=1152 bf16 = 144 16B-chunks in 36 K-tiles of 4 chunks. Within each
// aligned 4-chunk group, stored position p contains source chunk p ^ (r & 3), so the
// GEMM's linear global_load_lds staging + XOR-on-read gives conflict-free ds_read_b128
// (slot set {r*4 + (g ^ (r&3))} is a bijection onto the 64 16B slots).
__global__ __launch_bounds__(256) void k_im2col(const float* __restrict__ pred,
                                                const float* __restrict__ targ,
                                                u16* __restrict__ Ab, u16* __restrict__ Bb) {
  const int img = blockIdx.y;       // 0..5 : 0-1 pred, 2-5 target
  const int qy  = blockIdx.x;       // 0..45 real rows, 46-47 pad writer
  const int tid = threadIdx.x;
  const bool isA = img < 2;
  const float* image;
  u16* out;
  int rkc = 0;
  if (isA) {
    image = pred + (size_t)img * CC * HW2;
    out = Ab + (size_t)img * MROWS * KK;
  } else {
    int t = img - 2;                // (b*2 + kc)
    rkc = (t & 1) * NPK;
    image = targ + (size_t)t * CC * HW2;
    out = Bb + (size_t)(t >> 1) * NTOT * KK;
  }

  if (qy >= NHW) {                  // zero the 60 pad rows (2116..2175 of this set)
    int p0 = rkc + NQ + (qy - NHW) * 30;
    const u32x4 z = {0u, 0u, 0u, 0u};
    for (int i = tid; i < 30 * 144; i += 256) {
      int rr = i / 144, g = i - rr * 144;
      *reinterpret_cast<u32x4*>(out + ((size_t)(p0 + rr) * KK + g * 8)) = z;
    }
    return;
  }

  __shared__ float sI[CC * 144];    // [c][di*48+x], 73728 B
  __shared__ float sInv[144];

  for (int ch = tid; ch < CC * 36; ch += 256) {   // 36 float4 per channel
    int c = ch / 36, rem = ch - c * 36, di = rem / 12, j = rem - di * 12;
    float4 v = *reinterpret_cast<const float4*>(&image[(size_t)c * HW2 + (qy + di) * WW + j * 4]);
    *reinterpret_cast<float4*>(&sI[c * 144 + di * 48 + j * 4]) = v;
  }
  __syncthreads();
  for (int p = tid; p < 144; p += 256) {
    float s = 0.f;
    for (int c = 0; c < CC; ++c) { float v = sI[c * 144 + p]; s += v * v; }
    sInv[p] = 1.0f / fmaxf(sqrtf(s), 1e-12f);
  }
  __syncthreads();

  const int rb = rkc + qy * NHW;
  for (int g = tid; g < NHW * 144; g += 256) {
    int qx = g / 144, gg = g - qx * 144;
    int r = rb + qx;
    int sc = (gg & ~3) | ((gg & 3) ^ (r & 3));   // pre-swizzled source chunk
    int k0 = sc * 8;
    unsigned pack[4] = {0u, 0u, 0u, 0u};
    #pragma unroll
    for (int e = 0; e < 8; ++e) {
      int k = k0 + e;
      int c = k / 9, s9 = k - 9 * c;
      int di = s9 / 3, dj = s9 - 3 * di;
      int pix = di * 48 + qx + dj;
      float v = sI[c * 144 + pix] * sInv[pix];
      pack[e >> 1] |= ((unsigned)f2bf(v)) << ((e & 1) * 16);
    }
    u32x4 o; o.x = pack[0]; o.y = pack[1]; o.z = pack[2]; o.w = pack[3];
    *reinterpret_cast<u32x4*>(out + ((size_t)r * KK + gg * 8)) = o;
  }
}

// ---- kernel 2: 128x256 GEMM, 4 waves of 128x64, 3-buffer depth-2 counted-vmcnt ----
__global__ __launch_bounds__(256, 2) void k_gemm(const u16* __restrict__ Ab, const u16* __restrict__ Bb,
                                                 float* __restrict__ valp, int* __restrict__ idxp) {
  __shared__ u16 sA[3][128 * 32];   // 3 x 8 KB
  __shared__ u16 sB[3][256 * 32];   // 3 x 16 KB   (72 KB -> 2 blocks/CU)

  // XCD-aware bijective swizzle over 578 blocks (q=72, r=2), tm-fastest order
  const int w = blockIdx.x;
  const int xcd = w & 7, pos = w >> 3;
  const int swz = (xcd < 2 ? xcd * 73 : 2 * 73 + (xcd - 2) * 72) + pos;
  const int col = swz / 17;          // 0..33  (b*17 + tn)
  const int tm  = swz - col * 17;    // 0..16
  const int b   = col / 17;
  const int tn  = col - b * 17;

  const int tid = threadIdx.x, lane = tid & 63, wid = tid >> 6;  // wid = wave N-column
  const int r15 = lane & 15, g16 = lane >> 4;

  const u16* Abase = Ab + ((size_t)b * MROWS + (size_t)tm * 128) * KK;
  const u16* Bbase = Bb + ((size_t)b * NTOT + (size_t)tn * 256) * KK;

  // staging: slot s -> row = s>>2, chunk = s&3; LDS dest linear (slot*16B)
  const u16* aSrc[2];
  const u16* bSrc[4];
  #pragma unroll
  for (int i = 0; i < 2; ++i) {
    int s = i * 256 + tid;
    aSrc[i] = Abase + (size_t)(s >> 2) * KK + (s & 3) * 8;
  }
  #pragma unroll
  for (int i = 0; i < 4; ++i) {
    int s = i * 256 + tid;
    bSrc[i] = Bbase + (size_t)(s >> 2) * KK + (s & 3) * 8;
  }

  f32x4 acc[8][4];
  const f32x4 z4 = {0.f, 0.f, 0.f, 0.f};
  #pragma unroll
  for (int i = 0; i < 8; ++i)
    #pragma unroll
    for (int j = 0; j < 4; ++j) acc[i][j] = z4;

  auto stageH0 = [&](int buf, int kt) {            // 3 loads: a0, b0, b1
    __builtin_amdgcn_global_load_lds(
      (const __attribute__((address_space(1))) unsigned*)(aSrc[0] + kt * 32),
      (__attribute__((address_space(3))) unsigned*)&sA[buf][tid * 8], 16, 0, 0);
    #pragma unroll
    for (int i = 0; i < 2; ++i)
      __builtin_amdgcn_global_load_lds(
        (const __attribute__((address_space(1))) unsigned*)(bSrc[i] + kt * 32),
        (__attribute__((address_space(3))) unsigned*)&sB[buf][(i * 256 + tid) * 8], 16, 0, 0);
  };
  auto stageH1 = [&](int buf, int kt) {            // 3 loads: a1, b2, b3
    __builtin_amdgcn_global_load_lds(
      (const __attribute__((address_space(1))) unsigned*)(aSrc[1] + kt * 32),
      (__attribute__((address_space(3))) unsigned*)&sA[buf][(256 + tid) * 8], 16, 0, 0);
    #pragma unroll
    for (int i = 2; i < 4; ++i)
      __builtin_amdgcn_global_load_lds(
        (const __attribute__((address_space(1))) unsigned*)(bSrc[i] + kt * 32),
        (__attribute__((address_space(3))) unsigned*)&sB[buf][(i * 256 + tid) * 8], 16, 0, 0);
  };

  const int brow0 = wid * 64 + r15;                // + ni*16

  stageH0(0, 0); stageH1(0, 0);
  stageH0(1, 1); stageH1(1, 1);
  asm volatile("s_waitcnt vmcnt(6)" ::: "memory"); // tile 0 landed (own oldest 6)
  __builtin_amdgcn_s_barrier();                    // all waves' tile-0 loads landed

  int buf = 0;
  for (int kt = 0; kt < NKT; ++kt) {
    int nb = buf + 2; if (nb >= 3) nb -= 3;
    // ---- phase 1: B frags (reused both phases) + A rows 0..63; stage half of kt+2 ----
    short8 bfv[4], af[4];
    #pragma unroll
    for (int ni = 0; ni < 4; ++ni) {
      int row = brow0 + ni * 16;
      bfv[ni] = *reinterpret_cast<const short8*>(&sB[buf][row * 32 + ((g16 ^ (row & 3)) * 8)]);
    }
    #pragma unroll
    for (int mi = 0; mi < 4; ++mi) {
      int row = mi * 16 + r15;
      af[mi] = *reinterpret_cast<const short8*>(&sA[buf][row * 32 + ((g16 ^ (row & 3)) * 8)]);
    }
    if (kt + 2 < NKT) stageH0(nb, kt + 2);
    __builtin_amdgcn_s_barrier();
    asm volatile("s_waitcnt lgkmcnt(0)" ::: "memory");
    __builtin_amdgcn_sched_barrier(0);
    __builtin_amdgcn_s_setprio(1);
    #pragma unroll
    for (int mi = 0; mi < 4; ++mi)
      #pragma unroll
      for (int ni = 0; ni < 4; ++ni)
        acc[mi][ni] = __builtin_amdgcn_mfma_f32_16x16x32_bf16(af[mi], bfv[ni], acc[mi][ni], 0, 0, 0);
    __builtin_amdgcn_s_setprio(0);
    __builtin_amdgcn_s_barrier();

    // ---- phase 2: A rows 64..127 (B frags reused); stage other half of kt+2 ----
    short8 af2[4];
    #pragma unroll
    for (int mi = 0; mi < 4; ++mi) {
      int row = (mi + 4) * 16 + r15;
      af2[mi] = *reinterpret_cast<const short8*>(&sA[buf][row * 32 + ((g16 ^ (row & 3)) * 8)]);
    }
    if (kt + 2 < NKT) stageH1(nb, kt + 2);
    __builtin_amdgcn_s_barrier();
    asm volatile("s_waitcnt lgkmcnt(0)" ::: "memory");
    __builtin_amdgcn_sched_barrier(0);
    __builtin_amdgcn_s_setprio(1);
    #pragma unroll
    for (int mi = 0; mi < 4; ++mi)
      #pragma unroll
      for (int ni = 0; ni < 4; ++ni)
        acc[mi + 4][ni] = __builtin_amdgcn_mfma_f32_16x16x32_bf16(af2[mi], bfv[ni], acc[mi + 4][ni], 0, 0, 0);
    __builtin_amdgcn_s_setprio(0);

    // ---- tile boundary: counted wait (next tile landed, tile-after still flying) ----
    if (kt < NKT - 2)
      asm volatile("s_waitcnt vmcnt(6)" ::: "memory");
    else
      asm volatile("s_waitcnt vmcnt(0)" ::: "memory");
    __builtin_amdgcn_s_barrier();
    if (++buf == 3) buf = 0;
  }

  // fused epilogue: per row, max + first-wins argmax over this wave's 64 columns
  const int nb0 = tn * 256 + wid * 64;
  #pragma unroll
  for (int mi = 0; mi < 8; ++mi) {
    #pragma unroll
    for (int reg = 0; reg < 4; ++reg) {
      float bv = -3.0e38f; int bi = 0x7fffffff;
      #pragma unroll
      for (int ni = 0; ni < 4; ++ni) {
        int n = nb0 + ni * 16 + r15;
        int ns = n - (n >= NPK ? NPK : 0);
        float v = acc[mi][ni][reg];
        if (ns >= NQ) v = -3.0e38f;                    // mask pad columns
        bool take = (v > bv) || (v == bv && n < bi);
        bv = take ? v : bv;
        bi = take ? n : bi;
      }
      #pragma unroll
      for (int off = 1; off < 16; off <<= 1) {
        float ov = __shfl_xor(bv, off, 64);
        int   oi = __shfl_xor(bi, off, 64);
        bool take = (ov > bv) || (ov == bv && oi < bi);
        bv = take ? ov : bv;
        bi = take ? oi : bi;
      }
      if (r15 == 0) {
        int q = tm * 128 + mi * 16 + g16 * 4 + reg;
        size_t o = ((size_t)b * MROWS + q) * NHALF + (tn * 4 + wid);
        valp[o] = bv;
        idxp[o] = bi;
      }
    }
  }
}

// ---- kernel 3: wave-per-query argmax over 68 halves + raw-patch MSE ----
__global__ __launch_bounds__(256) void k_msearg(const float* __restrict__ pred, const float* __restrict__ targ,
                                                const float* __restrict__ valp, const int* __restrict__ idxp,
                                                float* __restrict__ msep) {
  int gw = (blockIdx.x * 256 + threadIdx.x) >> 6;
  int lane = threadIdx.x & 63;
  if (gw >= BATCH * NQ) return;
  int b = gw >= NQ ? 1 : 0;
  int q = gw - b * NQ;

  const float* vp = valp + ((size_t)b * MROWS + q) * NHALF;
  const int*   ip = idxp + ((size_t)b * MROWS + q) * NHALF;
  float bv = vp[lane];
  int   bi = ip[lane];
  if (lane < NHALF - 64) {
    float v1 = vp[64 + lane];
    int   i1 = ip[64 + lane];
    if (v1 > bv || (v1 == bv && i1 < bi)) { bv = v1; bi = i1; }
  }
  #pragma unroll
  for (int off = 1; off < 64; off <<= 1) {
    float ov = __shfl_xor(bv, off, 64);
    int   oi = __shfl_xor(bi, off, 64);
    bool take = (ov > bv) || (ov == bv && oi < bi);
    bv = take ? ov : bv;
    bi = take ? oi : bi;
  }
  int n = bi;
  int kc = n >= NPK ? 1 : 0;
  int ns = n - kc * NPK;
  ns = ns < NQ ? ns : NQ - 1;

  int qy = q / NHW, qx = q - qy * NHW;
  int ny = ns / NHW, nx = ns - ny * NHW;
  const float* P = pred + (size_t)b * CC * HW2;
  const float* T = targ + (size_t)(b * 2 + kc) * CC * HW2;
  float s = 0.f;
  for (int i = lane; i < CC * 9; i += 64) {
    int c = i / 9, sp = i - 9 * c;
    int di = sp / 3, dj = sp - 3 * di;
    float d = P[(size_t)c * HW2 + (qy + di) * WW + qx + dj]
            - T[(size_t)c * HW2 + (ny + di) * WW + nx + dj];
    s += d * d;
  }
  #pragma unroll
  for (int off = 1; off < 64; off <<= 1) s += __shfl_xor(s, off, 64);
  if (lane == 0) msep[gw] = s;
}

// ---- kernel 4: final deterministic reduction ----
__global__ void k_final(const float* __restrict__ msep, float* __restrict__ out) {
  int t = threadIdx.x;
  float s = 0.f;
  for (int i = t; i < BATCH * NQ; i += 256) s += msep[i];
  __shared__ float red[256];
  red[t] = s; __syncthreads();
  for (int st = 128; st > 0; st >>= 1) { if (t < st) red[t] += red[t + st]; __syncthreads(); }
  if (t == 0) out[0] = red[0] * (1.0f / 4875264.0f);   // 2*2116*128*9
}

extern "C" void kernel_launch(void* const* d_in, const int* in_sizes, int n_in,
                              void* d_out, int out_size, void* d_ws, size_t ws_size,
                              hipStream_t stream) {
  const float* pred = (const float*)d_in[0];
  const float* targ = (const float*)d_in[1];
  char* ws = (char*)d_ws;

  size_t offA = 0;
  size_t offB = offA + (size_t)BATCH * MROWS * KK * 2;      // 10,027,008
  size_t offV = offB + (size_t)BATCH * NTOT * KK * 2;       // 20,054,016
  size_t offI = offV + (size_t)BATCH * MROWS * NHALF * 4;   // 1,183,744
  size_t offM = offI + (size_t)BATCH * MROWS * NHALF * 4;   // 1,183,744

  u16*   Ab   = (u16*)(ws + offA);
  u16*   Bb   = (u16*)(ws + offB);
  float* valp = (float*)(ws + offV);
  int*   idxp = (int*)(ws + offI);
  float* msep = (float*)(ws + offM);

  k_im2col<<<dim3(48, 6), 256, 0, stream>>>(pred, targ, Ab, Bb);
  k_gemm<<<dim3(578), 256, 0, stream>>>(Ab, Bb, valp, idxp);
  k_msearg<<<dim3((BATCH * NQ + 3) / 4), 256, 0, stream>>>(pred, targ, valp, idxp, msep);
  k_final<<<1, 256, 0, stream>>>(msep, (float*)d_out);
}

// Round 6
// 127.637 us; speedup vs baseline: 1.1258x; 1.1258x over previous
//
#include <hip/hip_runtime.h>
#include <hip/hip_bf16.h>

typedef unsigned short u16;
typedef __attribute__((ext_vector_type(8))) short short8;
typedef __attribute__((ext_vector_type(4))) float f32x4;
typedef __attribute__((ext_vector_type(4))) unsigned int u32x4;

#define CC    128
#define WW    48
#define HW2   2304      // 48*48
#define NHW   46
#define NQ    2116      // 46*46
#define MROWS 2240      // padded M rows per batch (14*160)
#define NPK   2176      // rows per candidate set inside B
#define NTOT  4352      // 17*256
#define KK    1152      // 128*9
#define NKT   18        // K-tiles of 64
#define NHALF 68        // 17 N-tiles * 4 wave-columns
#define BATCH 2

__device__ __forceinline__ u16 f2bf(float f) {
  union { float f; unsigned u; } x; x.f = f;
  unsigned r = (x.u + 0x7fffu + ((x.u >> 16) & 1u)) >> 16;
  return (u16)r;
}

// ---- kernel 1: fused invnorm + im2col (bf16, pre-swizzled chunks), LDS-staged ----
// Row r holds K=1152 bf16 = 144 16B-chunks. Within each aligned 8-chunk group
// (one BK=64 K-tile), stored position p contains source chunk p ^ (r & 7), so the
// GEMM's linear global_load_lds staging + XOR-on-read gives conflict-free
// ds_read_b128 on 128B LDS rows (verified 0 conflicts in rounds 2-4).
__global__ __launch_bounds__(256) void k_im2col(const float* __restrict__ pred,
                                                const float* __restrict__ targ,
                                                u16* __restrict__ Ab, u16* __restrict__ Bb) {
  const int img = blockIdx.y;       // 0..5 : 0-1 pred, 2-5 target
  const int qy  = blockIdx.x;       // 0..45 real rows, 46-47 pad writer
  const int tid = threadIdx.x;
  const bool isA = img < 2;
  const float* image;
  u16* out;
  int rkc = 0;
  if (isA) {
    image = pred + (size_t)img * CC * HW2;
    out = Ab + (size_t)img * MROWS * KK;
  } else {
    int t = img - 2;                // (b*2 + kc)
    rkc = (t & 1) * NPK;
    image = targ + (size_t)t * CC * HW2;
    out = Bb + (size_t)(t >> 1) * NTOT * KK;
  }

  if (qy >= NHW) {                  // zero pad rows (A: 124/img, B: 60/set)
    int prow = isA ? 62 : 30;
    int p0 = rkc + NQ + (qy - NHW) * prow;
    const u32x4 z = {0u, 0u, 0u, 0u};
    for (int i = tid; i < prow * 144; i += 256) {
      int rr = i / 144, g = i - rr * 144;
      *reinterpret_cast<u32x4*>(out + ((size_t)(p0 + rr) * KK + g * 8)) = z;
    }
    return;
  }

  __shared__ float sI[CC * 144];    // [c][di*48+x], 73728 B
  __shared__ float sInv[144];

  for (int ch = tid; ch < CC * 36; ch += 256) {   // 36 float4 per channel
    int c = ch / 36, rem = ch - c * 36, di = rem / 12, j = rem - di * 12;
    float4 v = *reinterpret_cast<const float4*>(&image[(size_t)c * HW2 + (qy + di) * WW + j * 4]);
    *reinterpret_cast<float4*>(&sI[c * 144 + di * 48 + j * 4]) = v;
  }
  __syncthreads();
  for (int p = tid; p < 144; p += 256) {
    float s = 0.f;
    for (int c = 0; c < CC; ++c) { float v = sI[c * 144 + p]; s += v * v; }
    sInv[p] = 1.0f / fmaxf(sqrtf(s), 1e-12f);
  }
  __syncthreads();

  const int rb = rkc + qy * NHW;
  for (int g = tid; g < NHW * 144; g += 256) {
    int qx = g / 144, gg = g - qx * 144;
    int r = rb + qx;
    int sc = (gg & ~7) | ((gg & 7) ^ (r & 7));   // pre-swizzled source chunk
    int k0 = sc * 8;
    unsigned pack[4] = {0u, 0u, 0u, 0u};
    #pragma unroll
    for (int e = 0; e < 8; ++e) {
      int k = k0 + e;
      int c = k / 9, s9 = k - 9 * c;
      int di = s9 / 3, dj = s9 - 3 * di;
      int pix = di * 48 + qx + dj;
      float v = sI[c * 144 + pix] * sInv[pix];
      pack[e >> 1] |= ((unsigned)f2bf(v)) << ((e & 1) * 16);
    }
    u32x4 o; o.x = pack[0]; o.y = pack[1]; o.z = pack[2]; o.w = pack[3];
    *reinterpret_cast<u32x4*>(out + ((size_t)r * KK + gg * 8)) = o;
  }
}

// ---- kernel 2: 160x256 GEMM, 8 waves of 80x64, BK=64 dbuf, 4-phase interleave ----
__global__ __launch_bounds__(512, 2) void k_gemm(const u16* __restrict__ Ab, const u16* __restrict__ Bb,
                                                 float* __restrict__ valp, u16* __restrict__ idxp) {
  __shared__ u16 sA[2][160 * 64];   // 2 x 20 KB
  __shared__ u16 sB[2][256 * 64];   // 2 x 32 KB   (104 KB total)

  // XCD-aware bijective swizzle over 476 blocks (q=59, r=4), tm-fastest order
  const int w = blockIdx.x;
  const int xcd = w & 7, pos = w >> 3;
  const int swz = (xcd < 4 ? xcd * 60 : 240 + (xcd - 4) * 59) + pos;
  const int col = swz / 14;          // 0..33  (b*17 + tn)
  const int tm  = swz - col * 14;    // 0..13
  const int b   = col / 17;
  const int tn  = col - b * 17;

  const int tid = threadIdx.x, lane = tid & 63, wid = tid >> 6;
  const int wm = wid >> 2, wn = wid & 3;          // 2 M-halves x 4 N-quarters
  const int r15 = lane & 15, g16 = lane >> 4;

  const u16* Abase = Ab + ((size_t)b * MROWS + (size_t)tm * 160) * KK;
  const u16* Bbase = Bb + ((size_t)b * NTOT + (size_t)tn * 256) * KK;

  auto glds = [&](const u16* g, u16* l) {
    __builtin_amdgcn_global_load_lds((const __attribute__((address_space(1))) unsigned*)g,
                                     (__attribute__((address_space(3))) unsigned*)l, 16, 0, 0);
  };
  // staging: slot s -> row = s>>3, chunk = s&7; LDS dest linear (slot*16B)
  auto stA = [&](int bufi, int kt) {               // 1280 A slots: 2 or 3 loads/thread
    int s0 = tid, s1 = 512 + tid;
    glds(Abase + (size_t)(s0 >> 3) * KK + (size_t)kt * 64 + (s0 & 7) * 8, &sA[bufi][s0 * 8]);
    glds(Abase + (size_t)(s1 >> 3) * KK + (size_t)kt * 64 + (s1 & 7) * 8, &sA[bufi][s1 * 8]);
    if (tid < 256) {
      int s2 = 1024 + tid;
      glds(Abase + (size_t)(s2 >> 3) * KK + (size_t)kt * 64 + (s2 & 7) * 8, &sA[bufi][s2 * 8]);
    }
  };
  auto stB01 = [&](int bufi, int kt) {             // B slots 0..1023
    #pragma unroll
    for (int i = 0; i < 2; ++i) {
      int s = i * 512 + tid;
      glds(Bbase + (size_t)(s >> 3) * KK + (size_t)kt * 64 + (s & 7) * 8, &sB[bufi][s * 8]);
    }
  };
  auto stB23 = [&](int bufi, int kt) {             // B slots 1024..2047
    #pragma unroll
    for (int i = 2; i < 4; ++i) {
      int s = i * 512 + tid;
      glds(Bbase + (size_t)(s >> 3) * KK + (size_t)kt * 64 + (s & 7) * 8, &sB[bufi][s * 8]);
    }
  };

  f32x4 acc[5][4];
  const f32x4 z4 = {0.f, 0.f, 0.f, 0.f};
  #pragma unroll
  for (int i = 0; i < 5; ++i)
    #pragma unroll
    for (int j = 0; j < 4; ++j) acc[i][j] = z4;

  const int arow0 = wm * 80 + r15;                 // + mi*16
  const int brow0 = wn * 64 + r15;                 // + ni*16
  auto ldsoff = [&](int row, int c) { return row * 64 + ((c ^ (row & 7)) * 8); };

  short8 af[3], bfv[4];

  stA(0, 0); stB01(0, 0); stB23(0, 0);
  asm volatile("s_waitcnt vmcnt(0)" ::: "memory");
  __builtin_amdgcn_s_barrier();

  for (int kt = 0; kt < NKT; ++kt) {
    const int buf = kt & 1, nb = buf ^ 1;
    const bool pre = kt + 1 < NKT;

    // ---- P1: ks0, mi 0..2 (+ all B ks0); stage A of kt+1 ----
    #pragma unroll
    for (int mi = 0; mi < 3; ++mi)
      af[mi] = *reinterpret_cast<const short8*>(&sA[buf][ldsoff(arow0 + mi * 16, g16)]);
    #pragma unroll
    for (int ni = 0; ni < 4; ++ni)
      bfv[ni] = *reinterpret_cast<const short8*>(&sB[buf][ldsoff(brow0 + ni * 16, g16)]);
    if (pre) stA(nb, kt + 1);
    __builtin_amdgcn_s_barrier();
    asm volatile("s_waitcnt lgkmcnt(0)" ::: "memory");
    __builtin_amdgcn_sched_barrier(0);
    __builtin_amdgcn_s_setprio(1);
    #pragma unroll
    for (int mi = 0; mi < 3; ++mi)
      #pragma unroll
      for (int ni = 0; ni < 4; ++ni)
        acc[mi][ni] = __builtin_amdgcn_mfma_f32_16x16x32_bf16(af[mi], bfv[ni], acc[mi][ni], 0, 0, 0);
    __builtin_amdgcn_s_setprio(0);
    __builtin_amdgcn_s_barrier();

    // ---- P2: ks0, mi 3..4 (B reused); stage B01 of kt+1 ----
    #pragma unroll
    for (int mi = 0; mi < 2; ++mi)
      af[mi] = *reinterpret_cast<const short8*>(&sA[buf][ldsoff(arow0 + (mi + 3) * 16, g16)]);
    if (pre) stB01(nb, kt + 1);
    __builtin_amdgcn_s_barrier();
    asm volatile("s_waitcnt lgkmcnt(0)" ::: "memory");
    __builtin_amdgcn_sched_barrier(0);
    __builtin_amdgcn_s_setprio(1);
    #pragma unroll
    for (int mi = 0; mi < 2; ++mi)
      #pragma unroll
      for (int ni = 0; ni < 4; ++ni)
        acc[mi + 3][ni] = __builtin_amdgcn_mfma_f32_16x16x32_bf16(af[mi], bfv[ni], acc[mi + 3][ni], 0, 0, 0);
    __builtin_amdgcn_s_setprio(0);
    __builtin_amdgcn_s_barrier();

    // ---- P3: ks1, mi 0..2 (+ all B ks1); stage B23 of kt+1 ----
    #pragma unroll
    for (int mi = 0; mi < 3; ++mi)
      af[mi] = *reinterpret_cast<const short8*>(&sA[buf][ldsoff(arow0 + mi * 16, 4 + g16)]);
    #pragma unroll
    for (int ni = 0; ni < 4; ++ni)
      bfv[ni] = *reinterpret_cast<const short8*>(&sB[buf][ldsoff(brow0 + ni * 16, 4 + g16)]);
    if (pre) stB23(nb, kt + 1);
    __builtin_amdgcn_s_barrier();
    asm volatile("s_waitcnt lgkmcnt(0)" ::: "memory");
    __builtin_amdgcn_sched_barrier(0);
    __builtin_amdgcn_s_setprio(1);
    #pragma unroll
    for (int mi = 0; mi < 3; ++mi)
      #pragma unroll
      for (int ni = 0; ni < 4; ++ni)
        acc[mi][ni] = __builtin_amdgcn_mfma_f32_16x16x32_bf16(af[mi], bfv[ni], acc[mi][ni], 0, 0, 0);
    __builtin_amdgcn_s_setprio(0);
    __builtin_amdgcn_s_barrier();

    // ---- P4: ks1, mi 3..4 (B reused) ----
    #pragma unroll
    for (int mi = 0; mi < 2; ++mi)
      af[mi] = *reinterpret_cast<const short8*>(&sA[buf][ldsoff(arow0 + (mi + 3) * 16, 4 + g16)]);
    __builtin_amdgcn_s_barrier();
    asm volatile("s_waitcnt lgkmcnt(0)" ::: "memory");
    __builtin_amdgcn_sched_barrier(0);
    __builtin_amdgcn_s_setprio(1);
    #pragma unroll
    for (int mi = 0; mi < 2; ++mi)
      #pragma unroll
      for (int ni = 0; ni < 4; ++ni)
        acc[mi + 3][ni] = __builtin_amdgcn_mfma_f32_16x16x32_bf16(af[mi], bfv[ni], acc[mi + 3][ni], 0, 0, 0);
    __builtin_amdgcn_s_setprio(0);

    // ---- tile boundary: kt+1 loads issued >=3 phases ago -> cheap drain ----
    asm volatile("s_waitcnt vmcnt(0)" ::: "memory");
    __builtin_amdgcn_s_barrier();
  }

  // fused epilogue: per row, max + first-wins argmax over this wave's 64 columns
  const int nb0 = tn * 256 + wn * 64;
  #pragma unroll
  for (int mi = 0; mi < 5; ++mi) {
    #pragma unroll
    for (int reg = 0; reg < 4; ++reg) {
      float bv = -3.0e38f; int bi = 0x7fffffff;
      #pragma unroll
      for (int ni = 0; ni < 4; ++ni) {
        int n = nb0 + ni * 16 + r15;
        int ns = n - (n >= NPK ? NPK : 0);
        float v = acc[mi][ni][reg];
        if (ns >= NQ) v = -3.0e38f;                    // mask pad columns
        bool take = (v > bv) || (v == bv && n < bi);
        bv = take ? v : bv;
        bi = take ? n : bi;
      }
      #pragma unroll
      for (int off = 1; off < 16; off <<= 1) {
        float ov = __shfl_xor(bv, off, 64);
        int   oi = __shfl_xor(bi, off, 64);
        bool take = (ov > bv) || (ov == bv && oi < bi);
        bv = take ? ov : bv;
        bi = take ? oi : bi;
      }
      if (r15 == 0) {
        int q = tm * 160 + wm * 80 + mi * 16 + g16 * 4 + reg;
        size_t o = ((size_t)b * MROWS + q) * NHALF + (tn * 4 + wn);
        valp[o] = bv;
        idxp[o] = (u16)bi;
      }
    }
  }
}

// ---- kernel 3: wave-per-query argmax over 68 halves + raw-patch MSE ----
__global__ __launch_bounds__(256) void k_msearg(const float* __restrict__ pred, const float* __restrict__ targ,
                                                const float* __restrict__ valp, const u16* __restrict__ idxp,
                                                float* __restrict__ msep) {
  int gw = (blockIdx.x * 256 + threadIdx.x) >> 6;
  int lane = threadIdx.x & 63;
  if (gw >= BATCH * NQ) return;
  int b = gw >= NQ ? 1 : 0;
  int q = gw - b * NQ;

  const float* vp = valp + ((size_t)b * MROWS + q) * NHALF;
  const u16*   ip = idxp + ((size_t)b * MROWS + q) * NHALF;
  float bv = vp[lane];
  int   bi = ip[lane];
  if (lane < NHALF - 64) {
    float v1 = vp[64 + lane];
    int   i1 = ip[64 + lane];
    if (v1 > bv || (v1 == bv && i1 < bi)) { bv = v1; bi = i1; }
  }
  #pragma unroll
  for (int off = 1; off < 64; off <<= 1) {
    float ov = __shfl_xor(bv, off, 64);
    int   oi = __shfl_xor(bi, off, 64);
    bool take = (ov > bv) || (ov == bv && oi < bi);
    bv = take ? ov : bv;
    bi = take ? oi : bi;
  }
  int n = bi;
  int kc = n >= NPK ? 1 : 0;
  int ns = n - kc * NPK;
  ns = ns < NQ ? ns : NQ - 1;

  int qy = q / NHW, qx = q - qy * NHW;
  int ny = ns / NHW, nx = ns - ny * NHW;
  const float* P = pred + (size_t)b * CC * HW2;
  const float* T = targ + (size_t)(b * 2 + kc) * CC * HW2;
  float s = 0.f;
  for (int i = lane; i < CC * 9; i += 64) {
    int c = i / 9, sp = i - 9 * c;
    int di = sp / 3, dj = sp - 3 * di;
    float d = P[(size_t)c * HW2 + (qy + di) * WW + qx + dj]
            - T[(size_t)c * HW2 + (ny + di) * WW + nx + dj];
    s += d * d;
  }
  #pragma unroll
  for (int off = 1; off < 64; off <<= 1) s += __shfl_xor(s, off, 64);
  if (lane == 0) msep[gw] = s;
}

// ---- kernel 4: final deterministic reduction ----
__global__ void k_final(const float* __restrict__ msep, float* __restrict__ out) {
  int t = threadIdx.x;
  float s = 0.f;
  for (int i = t; i < BATCH * NQ; i += 256) s += msep[i];
  __shared__ float red[256];
  red[t] = s; __syncthreads();
  for (int st = 128; st > 0; st >>= 1) { if (t < st) red[t] += red[t + st]; __syncthreads(); }
  if (t == 0) out[0] = red[0] * (1.0f / 4875264.0f);   // 2*2116*128*9
}

extern "C" void kernel_launch(void* const* d_in, const int* in_sizes, int n_in,
                              void* d_out, int out_size, void* d_ws, size_t ws_size,
                              hipStream_t stream) {
  const float* pred = (const float*)d_in[0];
  const float* targ = (const float*)d_in[1];
  char* ws = (char*)d_ws;

  size_t offA = 0;
  size_t offB = offA + (size_t)BATCH * MROWS * KK * 2;      // 10,321,920
  size_t offV = offB + (size_t)BATCH * NTOT * KK * 2;       // 20,054,016
  size_t offI = offV + (size_t)BATCH * MROWS * NHALF * 4;   // 1,218,560
  size_t offM = offI + (size_t)BATCH * MROWS * NHALF * 2;   //   609,280

  u16*   Ab   = (u16*)(ws + offA);
  u16*   Bb   = (u16*)(ws + offB);
  float* valp = (float*)(ws + offV);
  u16*   idxp = (u16*)(ws + offI);
  float* msep = (float*)(ws + offM);

  k_im2col<<<dim3(48, 6), 256, 0, stream>>>(pred, targ, Ab, Bb);
  k_gemm<<<dim3(476), 512, 0, stream>>>(Ab, Bb, valp, idxp);
  k_msearg<<<dim3((BATCH * NQ + 3) / 4), 256, 0, stream>>>(pred, targ, valp, idxp, msep);
  k_final<<<1, 256, 0, stream>>>(msep, (float*)d_out);
}

// Round 8
// 116.896 us; speedup vs baseline: 1.2293x; 1.0919x over previous
//
#include <hip/hip_runtime.h>
#include <hip/hip_bf16.h>

typedef unsigned short u16;
typedef __attribute__((ext_vector_type(8))) short short8;
typedef __attribute__((ext_vector_type(4))) float f32x4;
typedef __attribute__((ext_vector_type(4))) unsigned int u32x4;

#define CC    128
#define WW    48
#define HW2   2304      // 48*48
#define NHW   46
#define NQ    2116      // 46*46
#define NPIX  2304      // pixels per image
#define DSTRIDE ((size_t)NPIX * NPIX + 64)   // D elems per set, +tail pad for 64-lane overrun
#define BATCH 2

__device__ __forceinline__ u16 f2bf(float f) {
  union { float f; unsigned u; } x; x.f = f;
  unsigned r = (x.u + 0x7fffu + ((x.u >> 16) & 1u)) >> 16;
  return (u16)r;
}
__device__ __forceinline__ float b2f(u16 v) {
  union { unsigned u; float f; } x; x.u = ((unsigned)v) << 16;
  return x.f;
}

// ---- kernel 1: per-pixel normalize + transpose to [pix][128c] bf16, chunk-swizzled ----
// Row r holds 128 bf16 = 16 16B-chunks in two 8-chunk groups (one per K-half of 64).
// Within each group, stored position p holds source chunk p ^ (r & 7) so the GEMM's
// linear global_load_lds staging + XOR-on-read is bank-conflict-free (proven R2/R4/R6).
__global__ __launch_bounds__(256) void k_norm(const float* __restrict__ pred,
                                              const float* __restrict__ targ,
                                              u16* __restrict__ PnT, u16* __restrict__ TnT) {
  const int img = blockIdx.y;          // 0..5 : 0-1 pred, 2-5 target
  const int p0  = blockIdx.x * 64;     // 36 blocks of 64 pixels
  const int tid = threadIdx.x;
  const float* src = img < 2 ? pred + (size_t)img * CC * HW2
                             : targ + (size_t)(img - 2) * CC * HW2;
  u16* out = img < 2 ? PnT + (size_t)img * NPIX * CC
                     : TnT + (size_t)(img - 2) * NPIX * CC;

  __shared__ float sT[64][129];        // transposed tile (+1 pad vs bank conflicts)
  __shared__ float sInv[64];

  #pragma unroll
  for (int it = 0; it < 32; ++it) {    // 128c x 64p loads, coalesced over p
    int idx = it * 256 + tid;
    int c = idx >> 6, p = idx & 63;
    sT[p][c] = src[(size_t)c * HW2 + p0 + p];
  }
  __syncthreads();
  if (tid < 64) {
    float s = 0.f;
    for (int c = 0; c < CC; ++c) { float v = sT[tid][c]; s += v * v; }
    sInv[tid] = 1.0f / fmaxf(sqrtf(s), 1e-12f);
  }
  __syncthreads();
  #pragma unroll
  for (int it = 0; it < 4; ++it) {     // 1024 16B-chunks, coalesced
    int cid = it * 256 + tid;
    int p = cid >> 4, g = cid & 15;
    int r = p0 + p;
    int sc = (g & ~7) | ((g & 7) ^ (r & 7));
    float inv = sInv[p];
    unsigned pack[4];
    #pragma unroll
    for (int e = 0; e < 8; ++e) {
      float v = sT[p][sc * 8 + e] * inv;
      if ((e & 1) == 0) pack[e >> 1] = (unsigned)f2bf(v);
      else              pack[e >> 1] |= ((unsigned)f2bf(v)) << 16;
    }
    u32x4 o; o.x = pack[0]; o.y = pack[1]; o.z = pack[2]; o.w = pack[3];
    *reinterpret_cast<u32x4*>(out + (size_t)r * CC + g * 8) = o;
  }
}

// ---- kernel 2: pixel-dot GEMM  D[s] = Pn[b] . Tn[b*2+s]^T  (2304x2304, K=128) ----
// 128x256 tile, 8 waves of 64x64, full K resident in LDS, single barrier.
__global__ __launch_bounds__(512) void k_pixdot(const u16* __restrict__ PnT, const u16* __restrict__ TnT,
                                                u16* __restrict__ D, int b) {
  __shared__ u16 sA[128 * 128];        // 32 KB = 2048 16B slots
  __shared__ u16 sB[256 * 128];        // 64 KB = 4096 16B slots
  const int nt = blockIdx.x, mt = blockIdx.y, s = blockIdx.z;
  const int tid = threadIdx.x, lane = tid & 63, wid = tid >> 6;
  const int wm = wid >> 2, wn = wid & 3;
  const int r15 = lane & 15, g16 = lane >> 4;

  const u16* Ab = PnT + (size_t)b * NPIX * CC + (size_t)mt * 128 * CC;
  const u16* Bb = TnT + (size_t)(b * 2 + s) * NPIX * CC + (size_t)nt * 256 * CC;
  u16* Dset = D + (size_t)s * DSTRIDE;

  // stage full K=128: slot -> row = sl>>4, chunk = sl&15; LDS dest linear slot*16B
  #pragma unroll
  for (int i = 0; i < 4; ++i) {        // 4*512 = 2048 A slots
    int sl = i * 512 + tid;
    __builtin_amdgcn_global_load_lds(
      (const __attribute__((address_space(1))) unsigned*)(Ab + (size_t)(sl >> 4) * CC + (sl & 15) * 8),
      (__attribute__((address_space(3))) unsigned*)&sA[sl * 8], 16, 0, 0);
  }
  #pragma unroll
  for (int i = 0; i < 8; ++i) {        // 8*512 = 4096 B slots
    int sl = i * 512 + tid;
    __builtin_amdgcn_global_load_lds(
      (const __attribute__((address_space(1))) unsigned*)(Bb + (size_t)(sl >> 4) * CC + (sl & 15) * 8),
      (__attribute__((address_space(3))) unsigned*)&sB[sl * 8], 16, 0, 0);
  }

  f32x4 acc[4][4];
  const f32x4 z4 = {0.f, 0.f, 0.f, 0.f};
  #pragma unroll
  for (int i = 0; i < 4; ++i)
    #pragma unroll
    for (int j = 0; j < 4; ++j) acc[i][j] = z4;

  asm volatile("s_waitcnt vmcnt(0)" ::: "memory");
  __builtin_amdgcn_s_barrier();

  const int arow0 = wm * 64 + r15;
  const int brow0 = wn * 64 + r15;
  #pragma unroll
  for (int ks = 0; ks < 4; ++ks) {     // K-step of 32; chunk = ks*4 + g16
    const int c = ks * 4 + g16;
    short8 af[4], bfv[4];
    #pragma unroll
    for (int mi = 0; mi < 4; ++mi) {
      int row = arow0 + mi * 16;
      af[mi] = *reinterpret_cast<const short8*>(
        &sA[row * 128 + (c >> 3) * 64 + (((c & 7) ^ (row & 7)) * 8)]);
    }
    #pragma unroll
    for (int ni = 0; ni < 4; ++ni) {
      int row = brow0 + ni * 16;
      bfv[ni] = *reinterpret_cast<const short8*>(
        &sB[row * 128 + (c >> 3) * 64 + (((c & 7) ^ (row & 7)) * 8)]);
    }
    __builtin_amdgcn_s_setprio(1);
    #pragma unroll
    for (int mi = 0; mi < 4; ++mi)
      #pragma unroll
      for (int ni = 0; ni < 4; ++ni)
        acc[mi][ni] = __builtin_amdgcn_mfma_f32_16x16x32_bf16(af[mi], bfv[ni], acc[mi][ni], 0, 0, 0);
    __builtin_amdgcn_s_setprio(0);
  }

  // store D tile as bf16
  const int m0 = mt * 128 + wm * 64, n0 = nt * 256 + wn * 64;
  #pragma unroll
  for (int mi = 0; mi < 4; ++mi)
    #pragma unroll
    for (int ni = 0; ni < 4; ++ni)
      #pragma unroll
      for (int rg = 0; rg < 4; ++rg) {
        int row = m0 + mi * 16 + g16 * 4 + rg;
        int col = n0 + ni * 16 + r15;
        Dset[(size_t)row * NPIX + col] = f2bf(acc[mi][ni][rg]);
      }
}

// ---- kernel 3: 9-tap stencil scores + argmax over all n + raw-patch MSE, per (q,b) ----
__global__ __launch_bounds__(256) void k_stencil(const u16* __restrict__ D,
                                                 const float* __restrict__ pred,
                                                 const float* __restrict__ targ,
                                                 float* __restrict__ msep, int b) {
  const int q = blockIdx.x;
  const int tid = threadIdx.x, lane = tid & 63, wid = tid >> 6;
  const int kc = wid >> 1, half = wid & 1;     // wave -> (candidate set, ny half)
  const int qy = q / NHW, qx = q - qy * NHW;
  const int qp = qy * WW + qx;

  const u16* Dset = D + (size_t)kc * DSTRIDE;
  const u16* pr[9];
  #pragma unroll
  for (int di = 0; di < 3; ++di)
    #pragma unroll
    for (int dj = 0; dj < 3; ++dj)
      pr[di * 3 + dj] = Dset + (size_t)(qp + di * WW + dj) * NPIX + dj + lane;

  float best = -3.0e38f; int bidx = 0x7fffffff;
  const bool valid = lane < NHW;
  const int ny0 = half * 23;
  for (int ny = ny0; ny < ny0 + 23; ++ny) {
    float sc = 0.f;
    #pragma unroll
    for (int di = 0; di < 3; ++di)
      #pragma unroll
      for (int dj = 0; dj < 3; ++dj)
        sc += b2f(pr[di * 3 + dj][(ny + di) * WW]);
    int n = kc * NQ + ny * NHW + lane;
    bool take = valid && (sc > best || (sc == best && n < bidx));
    best = take ? sc : best;
    bidx = take ? n : bidx;
  }
  #pragma unroll
  for (int off = 1; off < 64; off <<= 1) {
    float ov = __shfl_xor(best, off, 64);
    int   oi = __shfl_xor(bidx, off, 64);
    bool take = (ov > best) || (ov == best && oi < bidx);
    best = take ? ov : best;
    bidx = take ? oi : bidx;
  }

  __shared__ float sv[4]; __shared__ int si[4];
  __shared__ float red[256];
  if (lane == 0) { sv[wid] = best; si[wid] = bidx; }
  __syncthreads();
  float fb = sv[0]; int fi = si[0];
  #pragma unroll
  for (int wv = 1; wv < 4; ++wv) {
    bool take = (sv[wv] > fb) || (sv[wv] == fb && si[wv] < fi);
    fb = take ? sv[wv] : fb;
    fi = take ? si[wv] : fi;
  }

  // raw-patch MSE against the selected target patch
  int nkc = fi >= NQ ? 1 : 0;
  int ns = fi - nkc * NQ;
  int ny = ns / NHW, nx = ns - ny * NHW;
  const float* P = pred + (size_t)b * CC * HW2;
  const float* T = targ + (size_t)(b * 2 + nkc) * CC * HW2;
  float ssum = 0.f;
  for (int i = tid; i < CC * 9; i += 256) {
    int c = i / 9, sp = i - 9 * c;
    int di = sp / 3, dj = sp - 3 * di;
    float d = P[(size_t)c * HW2 + (qy + di) * WW + qx + dj]
            - T[(size_t)c * HW2 + (ny + di) * WW + nx + dj];
    ssum += d * d;
  }
  red[tid] = ssum; __syncthreads();
  for (int st = 128; st > 0; st >>= 1) { if (tid < st) red[tid] += red[tid + st]; __syncthreads(); }
  if (tid == 0) msep[b * NQ + q] = red[0];
}

// ---- kernel 4: final deterministic reduction ----
__global__ void k_final(const float* __restrict__ msep, float* __restrict__ out) {
  int t = threadIdx.x;
  float s = 0.f;
  for (int i = t; i < BATCH * NQ; i += 256) s += msep[i];
  __shared__ float red[256];
  red[t] = s; __syncthreads();
  for (int st = 128; st > 0; st >>= 1) { if (t < st) red[t] += red[t + st]; __syncthreads(); }
  if (t == 0) out[0] = red[0] * (1.0f / 4875264.0f);   // 2*2116*128*9
}

extern "C" void kernel_launch(void* const* d_in, const int* in_sizes, int n_in,
                              void* d_out, int out_size, void* d_ws, size_t ws_size,
                              hipStream_t stream) {
  const float* pred = (const float*)d_in[0];
  const float* targ = (const float*)d_in[1];
  char* ws = (char*)d_ws;

  size_t offP = 0;
  size_t offT = offP + (size_t)2 * NPIX * CC * 2;     // PnT: 1,179,648 B
  size_t offD = offT + (size_t)4 * NPIX * CC * 2;     // TnT: 2,359,296 B
  size_t offM = offD + (size_t)2 * DSTRIDE * 2;       // D (2 sets): 21,234,176 B

  u16*   PnT  = (u16*)(ws + offP);
  u16*   TnT  = (u16*)(ws + offT);
  u16*   Dbuf = (u16*)(ws + offD);
  float* msep = (float*)(ws + offM);                  // total ~24.8 MB

  k_norm<<<dim3(36, 6), 256, 0, stream>>>(pred, targ, PnT, TnT);
  k_pixdot<<<dim3(9, 18, 2), 512, 0, stream>>>(PnT, TnT, Dbuf, 0);
  k_stencil<<<dim3(NQ), 256, 0, stream>>>(Dbuf, pred, targ, msep, 0);
  k_pixdot<<<dim3(9, 18, 2), 512, 0, stream>>>(PnT, TnT, Dbuf, 1);
  k_stencil<<<dim3(NQ), 256, 0, stream>>>(Dbuf, pred, targ, msep, 1);
  k_final<<<1, 256, 0, stream>>>(msep, (float*)d_out);
}